// Round 4
// baseline (1074.062 us; speedup 1.0000x reference)
//
#include <hip/hip_runtime.h>

#define DIM 1536
#define NH 12
#define HD 128
#define S_LEN 5400
#define SPAD 5440      // 85*64  (kv tiles)
#define MPAD 5504      // 43*128 (GEMM M tiles / flash q tiles)
#define NQKV 4608
#define EPS_NORM 1e-6f

typedef __bf16 bf16_t;
typedef __bf16 bf16x8 __attribute__((ext_vector_type(8)));
typedef __bf16 bf16x4 __attribute__((ext_vector_type(4)));
typedef __bf16 bf16x2 __attribute__((ext_vector_type(2)));
typedef float  f32x4  __attribute__((ext_vector_type(4)));
typedef float  f32x16 __attribute__((ext_vector_type(16)));
typedef int    i32x2  __attribute__((ext_vector_type(2)));

// async global->LDS, 16B per lane; LDS dest is wave-uniform base + lane*16
#define GLOAD_LDS16(gp, lp) __builtin_amdgcn_global_load_lds( \
    (__attribute__((address_space(1))) void*)(void*)(gp),     \
    (__attribute__((address_space(3))) void*)(lp), 16, 0, 0)

// pack two f32 -> bf16x2 word (compiler emits cvt_pk; don't hand-write asm, m240)
__device__ __forceinline__ unsigned int pkbf(float a, float b) {
  union { bf16x2 h; unsigned int u; } c;
  c.h[0] = (__bf16)a; c.h[1] = (__bf16)b;
  return c.u;
}

// cross-half (lane ^ 32) reduce via permlane32_swap BUILTIN (two modeled defs,
// no register-coalescing hazard; max/sum of the result pair is direction-agnostic)
__device__ __forceinline__ float xhalf_max(float x) {
  i32x2 r = __builtin_amdgcn_permlane32_swap(__float_as_int(x), __float_as_int(x),
                                             false, false);
  return fmaxf(__int_as_float(r.x), __int_as_float(r.y));
}
__device__ __forceinline__ float xhalf_sum(float x) {
  i32x2 r = __builtin_amdgcn_permlane32_swap(__float_as_int(x), __float_as_int(x),
                                             false, false);
  return __int_as_float(r.x) + __int_as_float(r.y);
}

// ---------------- conversion kernels ----------------

__global__ __launch_bounds__(256) void cvt_x_kernel(const float* __restrict__ x,
                                                    bf16_t* __restrict__ xb) {
  size_t base = ((size_t)blockIdx.x * 256 + threadIdx.x) * 4;
  if (base >= (size_t)MPAD * DIM) return;
  size_t row = base / DIM;
  float4 v = make_float4(0.f, 0.f, 0.f, 0.f);
  if (row < S_LEN) v = *(const float4*)&x[base];
  bf16x4 o; o[0] = (__bf16)v.x; o[1] = (__bf16)v.y; o[2] = (__bf16)v.z; o[3] = (__bf16)v.w;
  *(bf16x4*)&xb[base] = o;
}

__global__ __launch_bounds__(256) void cvt_wqkv_kernel(const float* __restrict__ qw,
                                                       const float* __restrict__ kw,
                                                       const float* __restrict__ vw,
                                                       bf16_t* __restrict__ wb) {
  size_t base = ((size_t)blockIdx.x * 256 + threadIdx.x) * 4;
  if (base >= (size_t)NQKV * DIM) return;
  int row = (int)(base / DIM);
  int col = (int)(base - (size_t)row * DIM);
  const float* src; int rr = row;
  if (rr >= 3072)      { src = vw; rr -= 3072; }
  else if (rr >= 1536) { src = kw; rr -= 1536; }
  else                 { src = qw; }
  float4 v = *(const float4*)&src[(size_t)rr * DIM + col];
  bf16x4 o; o[0] = (__bf16)v.x; o[1] = (__bf16)v.y; o[2] = (__bf16)v.z; o[3] = (__bf16)v.w;
  *(bf16x4*)&wb[base] = o;
}

__global__ __launch_bounds__(256) void cvt_wo_kernel(const float* __restrict__ w,
                                                     bf16_t* __restrict__ wb) {
  size_t base = ((size_t)blockIdx.x * 256 + threadIdx.x) * 4;
  if (base >= (size_t)DIM * DIM) return;
  float4 v = *(const float4*)&w[base];
  bf16x4 o; o[0] = (__bf16)v.x; o[1] = (__bf16)v.y; o[2] = (__bf16)v.z; o[3] = (__bf16)v.w;
  *(bf16x4*)&wb[base] = o;
}

// ---------------- GEMM: C[M,N] = A[M,K] @ B[N,K]^T + bias ----------------
// 2-phase pipeline: prefetch k-tile t+1 into buf^1 while computing buf.

template<bool OUT_BF16>
__global__ __launch_bounds__(256) void gemm_bt_kernel(
    const bf16_t* __restrict__ A, const bf16_t* __restrict__ B, void* __restrict__ C,
    const float* __restrict__ bias0, const float* __restrict__ bias1,
    const float* __restrict__ bias2, int M, int N, int K, int Mvalid) {
  __shared__ bf16_t As[2][128 * 32];
  __shared__ bf16_t Bs[2][128 * 32];
  int tid = threadIdx.x;
  int lane = tid & 63, wave = tid >> 6, quad = lane >> 4, l16 = lane & 15;
  int m0 = blockIdx.y * 128, n0 = blockIdx.x * 128;
  int wm = (wave >> 1) * 64, wn = (wave & 1) * 64;
  const bf16_t* Ab = A + (size_t)m0 * K;
  const bf16_t* Bb = B + (size_t)n0 * K;
  f32x4 acc[4][4] = {};

  int eo0 = tid * 8;
  int row0 = eo0 >> 5, col0 = eo0 & 31;
  int eo1 = (256 + tid) * 8;
  int row1 = eo1 >> 5, col1 = eo1 & 31;

  // prologue: stage k-tile 0 into buf 0
  GLOAD_LDS16(Ab + (size_t)row0 * K + col0, &As[0][eo0]);
  GLOAD_LDS16(Bb + (size_t)row0 * K + col0, &Bs[0][eo0]);
  GLOAD_LDS16(Ab + (size_t)row1 * K + col1, &As[0][eo1]);
  GLOAD_LDS16(Bb + (size_t)row1 * K + col1, &Bs[0][eo1]);
  asm volatile("s_waitcnt vmcnt(0)" ::: "memory");
  __builtin_amdgcn_s_barrier();
  __builtin_amdgcn_sched_barrier(0);

  int KT = K >> 5;
  for (int t = 0; t < KT; t++) {
    int cur = t & 1;
    if (t + 1 < KT) {
      int kn = (t + 1) << 5;
      GLOAD_LDS16(Ab + (size_t)row0 * K + kn + col0, &As[cur ^ 1][eo0]);
      GLOAD_LDS16(Bb + (size_t)row0 * K + kn + col0, &Bs[cur ^ 1][eo0]);
      GLOAD_LDS16(Ab + (size_t)row1 * K + kn + col1, &As[cur ^ 1][eo1]);
      GLOAD_LDS16(Bb + (size_t)row1 * K + kn + col1, &Bs[cur ^ 1][eo1]);
    }
    bf16x8 af[4], bfr[4];
#pragma unroll
    for (int i = 0; i < 4; i++)
      af[i] = *(const bf16x8*)&As[cur][(wm + i * 16 + l16) * 32 + quad * 8];
#pragma unroll
    for (int j = 0; j < 4; j++)
      bfr[j] = *(const bf16x8*)&Bs[cur][(wn + j * 16 + l16) * 32 + quad * 8];
#pragma unroll
    for (int i = 0; i < 4; i++)
#pragma unroll
      for (int j = 0; j < 4; j++)
        acc[i][j] = __builtin_amdgcn_mfma_f32_16x16x32_bf16(af[i], bfr[j], acc[i][j], 0, 0, 0);
    asm volatile("s_waitcnt vmcnt(0) lgkmcnt(0)" ::: "memory");
    __builtin_amdgcn_s_barrier();
    __builtin_amdgcn_sched_barrier(0);
  }
  // epilogue: C/D layout col=lane&15, row=quad*4+reg  [m89-verified]
#pragma unroll
  for (int j = 0; j < 4; j++) {
    int n = n0 + wn + j * 16 + l16;
    float bias = (n < 1536) ? bias0[n] : (n < 3072) ? bias1[n - 1536] : bias2[n - 3072];
#pragma unroll
    for (int i = 0; i < 4; i++) {
#pragma unroll
      for (int r = 0; r < 4; r++) {
        int m = m0 + wm + i * 16 + quad * 4 + r;
        float v = acc[i][j][r] + bias;
        if (OUT_BF16) {
          ((bf16_t*)C)[(size_t)m * N + n] = (__bf16)v;
        } else {
          if (m < Mvalid) ((float*)C)[(size_t)m * N + n] = v;
        }
      }
    }
  }
}

// ---------------- RMSNorm + RoPE for q,k ----------------
// q pre-scaled by (1/sqrt(HD)) * log2(e) so flash uses raw v_exp_f32 (2^x)
// with no per-element multiply and no logit scale.

__global__ __launch_bounds__(256) void rope_qk_kernel(
    const bf16_t* __restrict__ qkv, const float* __restrict__ nqw,
    const float* __restrict__ nkw, const float* __restrict__ fcos,
    const float* __restrict__ fsin, bf16_t* __restrict__ qout,
    bf16_t* __restrict__ kout) {
  int s = blockIdx.x;              // 0..MPAD-1
  int tid = threadIdx.x;
  bool valid = s < S_LEN;
  int f = s / 900, hh = (s / 30) % 30, ww = s % 30;
  __shared__ float red[4];
  for (int which = 0; which < 2; which++) {
    const bf16_t* src = qkv + (size_t)s * NQKV + which * DIM;
    const float* nw = which ? nkw : nqw;
    bf16_t* dst = (which ? kout : qout) + (size_t)s * DIM;
    // 0.12751742686 = (1/sqrt(128)) * log2(e)
    float osc = which ? 1.0f : 0.12751742686f;
    float v[6]; float ss = 0.f;
#pragma unroll
    for (int i = 0; i < 6; i++) {
      v[i] = valid ? (float)src[tid * 6 + i] : 0.f;
      ss += v[i] * v[i];
    }
#pragma unroll
    for (int off = 32; off >= 1; off >>= 1) ss += __shfl_down(ss, off);
    if ((tid & 63) == 0) red[tid >> 6] = ss;
    __syncthreads();
    float tot = red[0] + red[1] + red[2] + red[3];
    float rn = rsqrtf(tot * (1.f / DIM) + EPS_NORM);
    __syncthreads();   // protect red[] before next `which` iteration
#pragma unroll
    for (int i = 0; i < 3; i++) {
      int e0 = tid * 6 + 2 * i;
      int p = e0 >> 1;             // pair index; cc = p&63
      int cc = p & 63;
      int pos = (cc < 22) ? f : (cc < 43) ? hh : ww;  // split [22,21,21]
      float c = fcos[pos * 64 + cc], sn = fsin[pos * 64 + cc];
      float xr = v[2 * i] * rn * nw[e0];
      float xi = v[2 * i + 1] * rn * nw[e0 + 1];
      dst[e0]     = (__bf16)((xr * c - xi * sn) * osc);
      dst[e0 + 1] = (__bf16)((xr * sn + xi * c) * osc);
    }
  }
}

// ---------------- V transpose: qkv v-part -> vt[h][d][s] ----------------

__global__ __launch_bounds__(256) void v_transpose_kernel(const bf16_t* __restrict__ qkv,
                                                          bf16_t* __restrict__ vt) {
  __shared__ bf16_t tile[64][136];   // +8 pad
  int h = blockIdx.y, s0 = blockIdx.x * 64, tid = threadIdx.x;
#pragma unroll
  for (int it = 0; it < 4; it++) {
    int eo = (it * 256 + tid) * 8;   // 64x128 elements
    int row = eo >> 7, col = eo & 127;
    int s = s0 + row;
    bf16x8 val = {};
    if (s < S_LEN) val = *(const bf16x8*)&qkv[(size_t)s * NQKV + 3072 + h * HD + col];
    *(bf16x8*)&tile[row][col] = val;
  }
  __syncthreads();
  int d = tid & 127, j0 = (tid >> 7) * 32;
  bf16x8 outv[4];
#pragma unroll
  for (int b = 0; b < 4; b++)
#pragma unroll
    for (int j = 0; j < 8; j++) outv[b][j] = tile[j0 + b * 8 + j][d];
  size_t base = ((size_t)h * HD + d) * SPAD + s0 + j0;
#pragma unroll
  for (int b = 0; b < 4; b++) *(bf16x8*)&vt[base + b * 8] = outv[b];
}

// ---------------- flash attention (S^T = K Q^T, 32x32x16 MFMA) ----------------
// kv-SPLIT: grid (43 q-tiles, 12 heads, 2 kv-halves) = 1032 blocks.
// Rationale: total wave contexts were grid-limited to 2/SIMD (OccupancyPercent
// ~12.5) -> dependency chains exposed. Splitting kv doubles contexts to
// 4/SIMD; single-buffered 32KB LDS lets 4 blocks/CU co-reside (R1 showed
// double-buffering gains nothing once >=2 independent blocks overlap).
// Each block emits unnormalized partial O (f32) + per-q (m,l) in log2 domain;
// combine_kernel merges the two halves.
// C/D 32x32 layout: col=lane&31, row=(reg&3)+8*(reg>>2)+4*(lane>>5)  [m74/m101]
// A/B frag: row/col=lane&31, k=(lane>>5)*8+j.

__global__ __launch_bounds__(256, 4) void flash_attn_kernel(
    const bf16_t* __restrict__ q, const bf16_t* __restrict__ k,
    const bf16_t* __restrict__ vt, float* __restrict__ op0,
    float* __restrict__ op1, float* __restrict__ mlp) {
  __shared__ __align__(16) char lds_raw[32768];
  bf16_t* Ks = (bf16_t*)lds_raw;             // 16 KB: [kv 64][k 128], 16B chunk c at pc = c^(row&15)
  bf16_t* Vs = (bf16_t*)(lds_raw + 16384);   // 16 KB: row r holds d=2r,2r+1; chunk c'=(d&1)*8+(kv>>3), pc=c'^(r&15)
  int head = blockIdx.y;
  int kvh = blockIdx.z;
  int s0 = blockIdx.x * 128;
  int tid = threadIdx.x, w = tid >> 6, lane = tid & 63;
  int l31 = lane & 31, hh = lane >> 5;

  // ---- Q B-frags from global (loop-invariant): B[col=q][k=16kc+8hh+j]
  bf16x8 bq[8];
  {
    const bf16_t* qp = &q[(size_t)(s0 + w * 32 + l31) * DIM + head * HD + hh * 8];
#pragma unroll
    for (int kc = 0; kc < 8; kc++) bq[kc] = *(const bf16x8*)(qp + kc * 16);
  }

  float m_i = -1e30f, l_i = 0.f;
  f32x16 oacc[4] = {};   // O^T: d = dt*32 + (r&3)+8*(r>>2)+4*hh, col q = l31

  int tstart = kvh ? 43 : 0;
  int tend   = kvh ? 85 : 43;   // 85 tiles total (SPAD/64)

  for (int t = tstart; t < tend; t++) {
    int kt = t * 64;

    // ---- stage K tile 64 kv x 128 k
#pragma unroll
    for (int it = 0; it < 4; it++) {
      int slot = it * 256 + tid;
      int row = slot >> 4, pc = slot & 15;
      int c = pc ^ (row & 15);
      GLOAD_LDS16(k + (size_t)(kt + row) * DIM + head * HD + c * 8, &Ks[slot * 8]);
    }
    // ---- stage V^T tile 128 d x 64 kv (d-pair interleaved rows)
#pragma unroll
    for (int it = 0; it < 4; it++) {
      int slot = it * 256 + tid;
      int row = slot >> 4, pc = slot & 15;
      int cp = pc ^ (row & 15);
      int d = 2 * row + (cp >> 3);
      GLOAD_LDS16(vt + ((size_t)head * HD + d) * SPAD + kt + (cp & 7) * 8, &Vs[slot * 8]);
    }
    asm volatile("s_waitcnt vmcnt(0)" ::: "memory");
    __builtin_amdgcn_s_barrier();
    __builtin_amdgcn_sched_barrier(0);

    // ---- S^T = K Q^T : 2 kv-tiles x 8 k-chunks of 32x32x16
    f32x16 sacc[2] = {};
    __builtin_amdgcn_s_setprio(1);
#pragma unroll
    for (int ns = 0; ns < 2; ns++) {
      int row = ns * 32 + l31;
#pragma unroll
      for (int kc = 0; kc < 8; kc++) {
        int pc = (kc * 2 + hh) ^ (row & 15);
        bf16x8 ak = *(const bf16x8*)&Ks[row * 128 + pc * 8];
        sacc[ns] = __builtin_amdgcn_mfma_f32_32x32x16_bf16(ak, bq[kc], sacc[ns], 0, 0, 0);
      }
    }
    __builtin_amdgcn_s_setprio(0);

    // ---- mask (final tile only)
    if (kt + 64 > S_LEN) {
#pragma unroll
      for (int ns = 0; ns < 2; ns++)
#pragma unroll
        for (int r = 0; r < 16; r++) {
          int kvg = kt + ns * 32 + (r & 3) + 8 * (r >> 2) + 4 * hh;
          if (kvg >= S_LEN) sacc[ns][r] = -1e30f;
        }
    }

    // ---- online softmax (log2 domain), tree max, permlane cross-half
    float mx;
    {
      float tm[8];
#pragma unroll
      for (int i = 0; i < 8; i++)
        tm[i] = fmaxf(fmaxf(sacc[0][i], sacc[0][i + 8]),
                      fmaxf(sacc[1][i], sacc[1][i + 8]));
#pragma unroll
      for (int i = 0; i < 4; i++) tm[i] = fmaxf(tm[i], tm[i + 4]);
      mx = fmaxf(fmaxf(tm[0], tm[2]), fmaxf(tm[1], tm[3]));
    }
    mx = xhalf_max(mx);
    if (!__all(mx - m_i <= 11.5f)) {   // 11.5 ~= 8*log2(e)
      float mn = fmaxf(m_i, mx);
      float al = __builtin_amdgcn_exp2f(m_i - mn);
      l_i *= al;
#pragma unroll
      for (int dt = 0; dt < 4; dt++)
#pragma unroll
        for (int r = 0; r < 16; r++) oacc[dt][r] *= al;
      m_i = mn;
    }
#pragma unroll
    for (int ns = 0; ns < 2; ns++)
#pragma unroll
      for (int r = 0; r < 16; r++)
        sacc[ns][r] = __builtin_amdgcn_exp2f(sacc[ns][r] - m_i);
    float rs;
    {
      float ts[8];
#pragma unroll
      for (int i = 0; i < 8; i++)
        ts[i] = (sacc[0][i] + sacc[0][i + 8]) + (sacc[1][i] + sacc[1][i + 8]);
#pragma unroll
      for (int i = 0; i < 4; i++) ts[i] += ts[i + 4];
      rs = (ts[0] + ts[2]) + (ts[1] + ts[3]);
    }
    l_i += xhalf_sum(rs);

    // ---- O^T += V^T P^T : in-register P (T12), 4 kv-chunks of 32x32x16
    // swap(w0,w2): r.x = low-kv word, r.y = high-kv word (m214-v22 recipe).
    __builtin_amdgcn_s_setprio(1);
#pragma unroll
    for (int kvc = 0; kvc < 4; kvc++) {
      int ns = kvc >> 1, rb = (kvc & 1) * 8;
      int w0 = (int)pkbf(sacc[ns][rb + 0], sacc[ns][rb + 1]);
      int w1 = (int)pkbf(sacc[ns][rb + 2], sacc[ns][rb + 3]);
      int w2 = (int)pkbf(sacc[ns][rb + 4], sacc[ns][rb + 5]);
      int w3 = (int)pkbf(sacc[ns][rb + 6], sacc[ns][rb + 7]);
      i32x2 r02 = __builtin_amdgcn_permlane32_swap(w0, w2, false, false);
      i32x2 r13 = __builtin_amdgcn_permlane32_swap(w1, w3, false, false);
      union { unsigned int u[4]; bf16x8 v8; } bpu;
      bpu.u[0] = (unsigned int)r02.x; bpu.u[1] = (unsigned int)r13.x;
      bpu.u[2] = (unsigned int)r02.y; bpu.u[3] = (unsigned int)r13.y;
      bf16x8 bp = bpu.v8;
#pragma unroll
      for (int dt = 0; dt < 4; dt++) {
        int d = dt * 32 + l31;
        int r = d >> 1;
        int cp = ((d & 1) << 3) | (kvc * 2 + hh);
        int pc = cp ^ (r & 15);
        bf16x8 av = *(const bf16x8*)&Vs[r * 128 + pc * 8];
        oacc[dt] = __builtin_amdgcn_mfma_f32_32x32x16_bf16(av, bp, oacc[dt], 0, 0, 0);
      }
    }
    __builtin_amdgcn_s_setprio(0);

    // ---- all waves done reading Ks/Vs before next stage overwrites
    asm volatile("s_waitcnt lgkmcnt(0)" ::: "memory");
    __builtin_amdgcn_s_barrier();
    __builtin_amdgcn_sched_barrier(0);
  }

  // ---- epilogue: unnormalized partial O^T -> per-wave LDS f32 transpose -> global
  // Ks/Vs dead after final barrier; per-wave 8KB f32 scratch [32 q][64 d-chunk'd]
  float* scrf = (float*)(lds_raw + (size_t)w * 8192);
  float* op = kvh ? op1 : op0;
  int qr = lane >> 1, seg = lane & 1;
  int srow = s0 + w * 32 + qr;
#pragma unroll
  for (int dhalf = 0; dhalf < 2; dhalf++) {
#pragma unroll
    for (int dl = 0; dl < 2; dl++) {
      int dt = dhalf * 2 + dl;
#pragma unroll
      for (int tt = 0; tt < 4; tt++) {
        f32x4 v;
#pragma unroll
        for (int r4 = 0; r4 < 4; r4++) v[r4] = oacc[dt][tt * 4 + r4];
        int c8 = dl * 8 + 2 * tt + hh;          // d chunk (dl*32 + 8tt + 4hh)/4
        int pc8 = c8 ^ (l31 & 15);
        *(f32x4*)&scrf[l31 * 64 + pc8 * 4] = v;
      }
    }
    // same-wave DS ordering guarantees write->read visibility (per-wave region)
#pragma unroll
    for (int i = 0; i < 4; i++) {
      int c8 = seg * 8 + 2 * i;
      f32x4 lo = *(const f32x4*)&scrf[qr * 64 + ((c8) ^ (qr & 15)) * 4];
      f32x4 hi = *(const f32x4*)&scrf[qr * 64 + ((c8 + 1) ^ (qr & 15)) * 4];
      size_t ob = ((size_t)srow * NH + head) * HD + dhalf * 64 + seg * 32 + i * 8;
      *(f32x4*)&op[ob] = lo;
      *(f32x4*)&op[ob + 4] = hi;
    }
  }
  // (m,l) per q, replicated across hh -> write from hh==0 lanes
  if (hh == 0) {
    int qg = s0 + w * 32 + l31;
    *(float2*)&mlp[(((size_t)kvh * NH + head) * MPAD + qg) * 2] = make_float2(m_i, l_i);
  }
}

// ---------------- combine: O = (O0*w0 + O1*w1) / (l0*w0 + l1*w1) ----------------

__global__ __launch_bounds__(256) void combine_kernel(
    const float* __restrict__ op0, const float* __restrict__ op1,
    const float* __restrict__ mlp, bf16_t* __restrict__ aob) {
  size_t idx = (size_t)blockIdx.x * 256 + threadIdx.x;   // one f32x4 per thread
  if (idx >= (size_t)MPAD * NH * 32) return;
  int dc = (int)(idx & 31);
  int head = (int)((idx >> 5) % NH);
  int s = (int)(idx / (NH * 32));
  float2 a0 = *(const float2*)&mlp[(((size_t)0 * NH + head) * MPAD + s) * 2];
  float2 a1 = *(const float2*)&mlp[(((size_t)1 * NH + head) * MPAD + s) * 2];
  float m = fmaxf(a0.x, a1.x);
  float w0 = __builtin_amdgcn_exp2f(a0.x - m);   // log2-domain weights
  float w1 = __builtin_amdgcn_exp2f(a1.x - m);
  float inv = 1.f / (a0.y * w0 + a1.y * w1);
  w0 *= inv; w1 *= inv;
  size_t ob = ((size_t)s * NH + head) * HD + (size_t)dc * 4;
  f32x4 x0 = *(const f32x4*)&op0[ob];
  f32x4 x1 = *(const f32x4*)&op1[ob];
  bf16x4 o4;
#pragma unroll
  for (int j = 0; j < 4; j++) o4[j] = (__bf16)(x0[j] * w0 + x1[j] * w1);
  *(bf16x4*)&aob[ob] = o4;   // == s*DIM + head*HD + d
}

// ---------------- launch ----------------

extern "C" void kernel_launch(void* const* d_in, const int* in_sizes, int n_in,
                              void* d_out, int out_size, void* d_ws, size_t ws_size,
                              hipStream_t stream) {
  const float* x    = (const float*)d_in[0];
  const float* q_w  = (const float*)d_in[1];
  const float* q_b  = (const float*)d_in[2];
  const float* k_w  = (const float*)d_in[3];
  const float* k_b  = (const float*)d_in[4];
  const float* v_w  = (const float*)d_in[5];
  const float* v_b  = (const float*)d_in[6];
  const float* o_w  = (const float*)d_in[7];
  const float* o_b  = (const float*)d_in[8];
  const float* nqw  = (const float*)d_in[9];
  const float* nkw  = (const float*)d_in[10];
  const float* fcos = (const float*)d_in[11];
  const float* fsin = (const float*)d_in[12];

  char* ws = (char*)d_ws;
  bf16_t* xb   = (bf16_t*)(ws + 0);          // 16,908,288 B
  bf16_t* wqkv = (bf16_t*)(ws + 16908288);   // 14,155,776 B
  bf16_t* wob  = (bf16_t*)(ws + 31064064);   //  4,718,592 B
  bf16_t* qkv  = (bf16_t*)(ws + 35782656);   // 50,724,864 B
  bf16_t* qb   = (bf16_t*)(ws + 86507520);   // 16,908,288 B
  bf16_t* kb   = (bf16_t*)(ws + 103415808);  // 16,908,288 B
  bf16_t* vtb  = (bf16_t*)(ws + 0);          // alias xb (dead after GEMM1)
  float*  op0p = (float*)(ws + 35782656);    // alias qkv (dead after rope+transpose), 33,816,576 B
  float*  op1p = (float*)(ws + 120324096);   // 33,816,576 B
  float*  mlpp = (float*)(ws + 154140672);   //  1,056,768 B  (ws end ~155.2 MB)
  bf16_t* aob  = (bf16_t*)(ws + 103415808);  // alias kb (dead after flash)

  cvt_x_kernel<<<(MPAD * DIM / 4 + 255) / 256, 256, 0, stream>>>(x, xb);
  cvt_wqkv_kernel<<<(NQKV * DIM / 4 + 255) / 256, 256, 0, stream>>>(q_w, k_w, v_w, wqkv);
  cvt_wo_kernel<<<(DIM * DIM / 4 + 255) / 256, 256, 0, stream>>>(o_w, wob);

  gemm_bt_kernel<true><<<dim3(NQKV / 128, MPAD / 128), 256, 0, stream>>>(
      xb, wqkv, qkv, q_b, k_b, v_b, MPAD, NQKV, DIM, MPAD);

  rope_qk_kernel<<<MPAD, 256, 0, stream>>>(qkv, nqw, nkw, fcos, fsin, qb, kb);
  v_transpose_kernel<<<dim3(SPAD / 64, NH), 256, 0, stream>>>(qkv, vtb);

  flash_attn_kernel<<<dim3(MPAD / 128, NH, 2), 256, 0, stream>>>(
      qb, kb, vtb, op0p, op1p, mlpp);

  combine_kernel<<<(MPAD * NH * 32 + 255) / 256, 256, 0, stream>>>(
      op0p, op1p, mlpp, aob);

  gemm_bt_kernel<false><<<dim3(DIM / 128, MPAD / 128), 256, 0, stream>>>(
      aob, wob, d_out, o_b, o_b, o_b, MPAD, DIM, DIM, S_LEN);
}

// Round 5
// 657.069 us; speedup vs baseline: 1.6346x; 1.6346x over previous
//
#include <hip/hip_runtime.h>

#define DIM 1536
#define NH 12
#define HD 128
#define S_LEN 5400
#define SPAD 5504      // 43*128  (kv tiles of 128)
#define MPAD 5504      // 43*128 (GEMM M tiles / flash q tiles)
#define NQKV 4608
#define EPS_NORM 1e-6f

typedef __bf16 bf16_t;
typedef __bf16 bf16x8 __attribute__((ext_vector_type(8)));
typedef __bf16 bf16x4 __attribute__((ext_vector_type(4)));
typedef __bf16 bf16x2 __attribute__((ext_vector_type(2)));
typedef float  f32x4  __attribute__((ext_vector_type(4)));
typedef float  f32x16 __attribute__((ext_vector_type(16)));
typedef int    i32x2  __attribute__((ext_vector_type(2)));

// async global->LDS, 16B per lane; LDS dest is wave-uniform base + lane*16
#define GLOAD_LDS16(gp, lp) __builtin_amdgcn_global_load_lds( \
    (__attribute__((address_space(1))) void*)(void*)(gp),     \
    (__attribute__((address_space(3))) void*)(lp), 16, 0, 0)

// pack two f32 -> bf16x2 word (compiler emits cvt_pk; don't hand-write asm, m240)
__device__ __forceinline__ unsigned int pkbf(float a, float b) {
  union { bf16x2 h; unsigned int u; } c;
  c.h[0] = (__bf16)a; c.h[1] = (__bf16)b;
  return c.u;
}

// cross-half (lane ^ 32) reduce via permlane32_swap BUILTIN (two modeled defs,
// no register-coalescing hazard; max/sum of the result pair is direction-agnostic)
__device__ __forceinline__ float xhalf_max(float x) {
  i32x2 r = __builtin_amdgcn_permlane32_swap(__float_as_int(x), __float_as_int(x),
                                             false, false);
  return fmaxf(__int_as_float(r.x), __int_as_float(r.y));
}
__device__ __forceinline__ float xhalf_sum(float x) {
  i32x2 r = __builtin_amdgcn_permlane32_swap(__float_as_int(x), __float_as_int(x),
                                             false, false);
  return __int_as_float(r.x) + __int_as_float(r.y);
}

// ---------------- conversion kernels ----------------

__global__ __launch_bounds__(256) void cvt_x_kernel(const float* __restrict__ x,
                                                    bf16_t* __restrict__ xb) {
  size_t base = ((size_t)blockIdx.x * 256 + threadIdx.x) * 4;
  if (base >= (size_t)MPAD * DIM) return;
  size_t row = base / DIM;
  float4 v = make_float4(0.f, 0.f, 0.f, 0.f);
  if (row < S_LEN) v = *(const float4*)&x[base];
  bf16x4 o; o[0] = (__bf16)v.x; o[1] = (__bf16)v.y; o[2] = (__bf16)v.z; o[3] = (__bf16)v.w;
  *(bf16x4*)&xb[base] = o;
}

__global__ __launch_bounds__(256) void cvt_wqkv_kernel(const float* __restrict__ qw,
                                                       const float* __restrict__ kw,
                                                       const float* __restrict__ vw,
                                                       bf16_t* __restrict__ wb) {
  size_t base = ((size_t)blockIdx.x * 256 + threadIdx.x) * 4;
  if (base >= (size_t)NQKV * DIM) return;
  int row = (int)(base / DIM);
  int col = (int)(base - (size_t)row * DIM);
  const float* src; int rr = row;
  if (rr >= 3072)      { src = vw; rr -= 3072; }
  else if (rr >= 1536) { src = kw; rr -= 1536; }
  else                 { src = qw; }
  float4 v = *(const float4*)&src[(size_t)rr * DIM + col];
  bf16x4 o; o[0] = (__bf16)v.x; o[1] = (__bf16)v.y; o[2] = (__bf16)v.z; o[3] = (__bf16)v.w;
  *(bf16x4*)&wb[base] = o;
}

__global__ __launch_bounds__(256) void cvt_wo_kernel(const float* __restrict__ w,
                                                     bf16_t* __restrict__ wb) {
  size_t base = ((size_t)blockIdx.x * 256 + threadIdx.x) * 4;
  if (base >= (size_t)DIM * DIM) return;
  float4 v = *(const float4*)&w[base];
  bf16x4 o; o[0] = (__bf16)v.x; o[1] = (__bf16)v.y; o[2] = (__bf16)v.z; o[3] = (__bf16)v.w;
  *(bf16x4*)&wb[base] = o;
}

// ---------------- GEMM: C[M,N] = A[M,K] @ B[N,K]^T + bias ----------------
// 2-phase pipeline: prefetch k-tile t+1 into buf^1 while computing buf.

template<bool OUT_BF16>
__global__ __launch_bounds__(256) void gemm_bt_kernel(
    const bf16_t* __restrict__ A, const bf16_t* __restrict__ B, void* __restrict__ C,
    const float* __restrict__ bias0, const float* __restrict__ bias1,
    const float* __restrict__ bias2, int M, int N, int K, int Mvalid) {
  __shared__ bf16_t As[2][128 * 32];
  __shared__ bf16_t Bs[2][128 * 32];
  int tid = threadIdx.x;
  int lane = tid & 63, wave = tid >> 6, quad = lane >> 4, l16 = lane & 15;
  int m0 = blockIdx.y * 128, n0 = blockIdx.x * 128;
  int wm = (wave >> 1) * 64, wn = (wave & 1) * 64;
  const bf16_t* Ab = A + (size_t)m0 * K;
  const bf16_t* Bb = B + (size_t)n0 * K;
  f32x4 acc[4][4] = {};

  int eo0 = tid * 8;
  int row0 = eo0 >> 5, col0 = eo0 & 31;
  int eo1 = (256 + tid) * 8;
  int row1 = eo1 >> 5, col1 = eo1 & 31;

  // prologue: stage k-tile 0 into buf 0
  GLOAD_LDS16(Ab + (size_t)row0 * K + col0, &As[0][eo0]);
  GLOAD_LDS16(Bb + (size_t)row0 * K + col0, &Bs[0][eo0]);
  GLOAD_LDS16(Ab + (size_t)row1 * K + col1, &As[0][eo1]);
  GLOAD_LDS16(Bb + (size_t)row1 * K + col1, &Bs[0][eo1]);
  asm volatile("s_waitcnt vmcnt(0)" ::: "memory");
  __builtin_amdgcn_s_barrier();
  __builtin_amdgcn_sched_barrier(0);

  int KT = K >> 5;
  for (int t = 0; t < KT; t++) {
    int cur = t & 1;
    if (t + 1 < KT) {
      int kn = (t + 1) << 5;
      GLOAD_LDS16(Ab + (size_t)row0 * K + kn + col0, &As[cur ^ 1][eo0]);
      GLOAD_LDS16(Bb + (size_t)row0 * K + kn + col0, &Bs[cur ^ 1][eo0]);
      GLOAD_LDS16(Ab + (size_t)row1 * K + kn + col1, &As[cur ^ 1][eo1]);
      GLOAD_LDS16(Bb + (size_t)row1 * K + kn + col1, &Bs[cur ^ 1][eo1]);
    }
    bf16x8 af[4], bfr[4];
#pragma unroll
    for (int i = 0; i < 4; i++)
      af[i] = *(const bf16x8*)&As[cur][(wm + i * 16 + l16) * 32 + quad * 8];
#pragma unroll
    for (int j = 0; j < 4; j++)
      bfr[j] = *(const bf16x8*)&Bs[cur][(wn + j * 16 + l16) * 32 + quad * 8];
#pragma unroll
    for (int i = 0; i < 4; i++)
#pragma unroll
      for (int j = 0; j < 4; j++)
        acc[i][j] = __builtin_amdgcn_mfma_f32_16x16x32_bf16(af[i], bfr[j], acc[i][j], 0, 0, 0);
    asm volatile("s_waitcnt vmcnt(0) lgkmcnt(0)" ::: "memory");
    __builtin_amdgcn_s_barrier();
    __builtin_amdgcn_sched_barrier(0);
  }
  // epilogue: C/D layout col=lane&15, row=quad*4+reg  [m89-verified]
#pragma unroll
  for (int j = 0; j < 4; j++) {
    int n = n0 + wn + j * 16 + l16;
    float bias = (n < 1536) ? bias0[n] : (n < 3072) ? bias1[n - 1536] : bias2[n - 3072];
#pragma unroll
    for (int i = 0; i < 4; i++) {
#pragma unroll
      for (int r = 0; r < 4; r++) {
        int m = m0 + wm + i * 16 + quad * 4 + r;
        float v = acc[i][j][r] + bias;
        if (OUT_BF16) {
          ((bf16_t*)C)[(size_t)m * N + n] = (__bf16)v;
        } else {
          if (m < Mvalid) ((float*)C)[(size_t)m * N + n] = v;
        }
      }
    }
  }
}

// ---------------- RMSNorm + RoPE for q,k ----------------
// q pre-scaled by (1/sqrt(HD)) * log2(e) so flash uses raw v_exp_f32 (2^x)
// with no per-element multiply and no logit scale.

__global__ __launch_bounds__(256) void rope_qk_kernel(
    const bf16_t* __restrict__ qkv, const float* __restrict__ nqw,
    const float* __restrict__ nkw, const float* __restrict__ fcos,
    const float* __restrict__ fsin, bf16_t* __restrict__ qout,
    bf16_t* __restrict__ kout) {
  int s = blockIdx.x;              // 0..MPAD-1
  int tid = threadIdx.x;
  bool valid = s < S_LEN;
  int f = s / 900, hh = (s / 30) % 30, ww = s % 30;
  __shared__ float red[4];
  for (int which = 0; which < 2; which++) {
    const bf16_t* src = qkv + (size_t)s * NQKV + which * DIM;
    const float* nw = which ? nkw : nqw;
    bf16_t* dst = (which ? kout : qout) + (size_t)s * DIM;
    // 0.12751742686 = (1/sqrt(128)) * log2(e)
    float osc = which ? 1.0f : 0.12751742686f;
    float v[6]; float ss = 0.f;
#pragma unroll
    for (int i = 0; i < 6; i++) {
      v[i] = valid ? (float)src[tid * 6 + i] : 0.f;
      ss += v[i] * v[i];
    }
#pragma unroll
    for (int off = 32; off >= 1; off >>= 1) ss += __shfl_down(ss, off);
    if ((tid & 63) == 0) red[tid >> 6] = ss;
    __syncthreads();
    float tot = red[0] + red[1] + red[2] + red[3];
    float rn = rsqrtf(tot * (1.f / DIM) + EPS_NORM);
    __syncthreads();   // protect red[] before next `which` iteration
#pragma unroll
    for (int i = 0; i < 3; i++) {
      int e0 = tid * 6 + 2 * i;
      int p = e0 >> 1;             // pair index; cc = p&63
      int cc = p & 63;
      int pos = (cc < 22) ? f : (cc < 43) ? hh : ww;  // split [22,21,21]
      float c = fcos[pos * 64 + cc], sn = fsin[pos * 64 + cc];
      float xr = v[2 * i] * rn * nw[e0];
      float xi = v[2 * i + 1] * rn * nw[e0 + 1];
      dst[e0]     = (__bf16)((xr * c - xi * sn) * osc);
      dst[e0 + 1] = (__bf16)((xr * sn + xi * c) * osc);
    }
  }
}

// ---------------- V transpose: qkv v-part -> vt[h][d][s] ----------------

__global__ __launch_bounds__(256) void v_transpose_kernel(const bf16_t* __restrict__ qkv,
                                                          bf16_t* __restrict__ vt) {
  __shared__ bf16_t tile[64][136];   // +8 pad
  int h = blockIdx.y, s0 = blockIdx.x * 64, tid = threadIdx.x;
#pragma unroll
  for (int it = 0; it < 4; it++) {
    int eo = (it * 256 + tid) * 8;   // 64x128 elements
    int row = eo >> 7, col = eo & 127;
    int s = s0 + row;
    bf16x8 val = {};
    if (s < S_LEN) val = *(const bf16x8*)&qkv[(size_t)s * NQKV + 3072 + h * HD + col];
    *(bf16x8*)&tile[row][col] = val;
  }
  __syncthreads();
  int d = tid & 127, j0 = (tid >> 7) * 32;
  bf16x8 outv[4];
#pragma unroll
  for (int b = 0; b < 4; b++)
#pragma unroll
    for (int j = 0; j < 8; j++) outv[b][j] = tile[j0 + b * 8 + j][d];
  size_t base = ((size_t)h * HD + d) * SPAD + s0 + j0;
#pragma unroll
  for (int b = 0; b < 4; b++) *(bf16x8*)&vt[base + b * 8] = outv[b];
}

// ---------------- flash attention (S^T = K Q^T, 32x32x16 MFMA) ----------------
// REVERTED from R4's kv-split (traffic disaster: FETCH 144MB->1.5GB).
// This round: KVBLK 64->128 (43 iterations instead of 85) to amortize the
// per-tile fixed overhead (2 barriers, vmcnt drain, tree-reduce + permlanes +
// __all + rescale check) which dominates at 2 blocks/CU overlap. Single-buffered
// 64KB LDS (R1: prefetch ~= single-buffer once 2 blocks overlap).
// Flattened 1D grid + bijective XCD-chunked swizzle (m204): each XCD's blocks
// cluster on ~1.5 heads -> per-XCD K/V working set ~4.2MB ~= L2.
// C/D 32x32 layout: col=lane&31, row=(reg&3)+8*(reg>>2)+4*(lane>>5)  [m74/m101]
// A/B frag: row/col=lane&31, k=(lane>>5)*8+j.

__global__ __launch_bounds__(256, 2) void flash_attn_kernel(
    const bf16_t* __restrict__ q, const bf16_t* __restrict__ k,
    const bf16_t* __restrict__ vt, bf16_t* __restrict__ o) {
  __shared__ __align__(16) char lds_raw[65536];
  bf16_t* Ks = (bf16_t*)lds_raw;             // 32 KB: [kv 128][k 128], 16B chunk c at pc = c^(row&15)
  bf16_t* Vs = (bf16_t*)(lds_raw + 32768);   // 2 x 16 KB kv-halves; each: row r holds d=2r,2r+1,
                                             //   chunk c'=(d&1)*8+(kvlocal>>3), pc=c'^(r&15)
  // bijective XCD-chunked swizzle: HW round-robins XCD by blockIdx%8; give
  // XCD c a CONTIGUOUS work range so same-head blocks share one L2.
  int nwg = gridDim.x;                 // 516
  int bid = blockIdx.x;
  int xcd = bid & 7, idx = bid >> 3;
  int q8 = nwg >> 3, rr = nwg & 7;
  int work = (xcd < rr ? xcd * (q8 + 1) : rr * (q8 + 1) + (xcd - rr) * q8) + idx;
  int head = work / 43;
  int s0 = (work - head * 43) * 128;

  int tid = threadIdx.x, w = tid >> 6, lane = tid & 63;
  int l31 = lane & 31, hh = lane >> 5;

  // ---- Q B-frags from global (loop-invariant): B[col=q][k=16kc+8hh+j]
  bf16x8 bq[8];
  {
    const bf16_t* qp = &q[(size_t)(s0 + w * 32 + l31) * DIM + head * HD + hh * 8];
#pragma unroll
    for (int kc = 0; kc < 8; kc++) bq[kc] = *(const bf16x8*)(qp + kc * 16);
  }

  float m_i = -1e30f, l_i = 0.f;
  f32x16 oacc[4] = {};   // O^T: d = dt*32 + (r&3)+8*(r>>2)+4*hh, col q = l31

  const int NT = SPAD / 128;   // 43

  for (int t = 0; t < NT; t++) {
    int kt = t * 128;

    // ---- stage K tile 128 kv x 128 k (8 gload/thread)
#pragma unroll
    for (int it = 0; it < 8; it++) {
      int slot = it * 256 + tid;
      int row = slot >> 4, pc = slot & 15;
      int c = pc ^ (row & 15);
      GLOAD_LDS16(k + (size_t)(kt + row) * DIM + head * HD + c * 8, &Ks[slot * 8]);
    }
    // ---- stage V^T as 2 kv-halves of 128 d x 64 kv (d-pair interleaved rows)
#pragma unroll
    for (int h2 = 0; h2 < 2; h2++)
#pragma unroll
      for (int it = 0; it < 4; it++) {
        int slot = it * 256 + tid;
        int row = slot >> 4, pc = slot & 15;
        int cp = pc ^ (row & 15);
        int d = 2 * row + (cp >> 3);
        GLOAD_LDS16(vt + ((size_t)head * HD + d) * SPAD + kt + h2 * 64 + (cp & 7) * 8,
                    &Vs[h2 * 8192 + slot * 8]);
      }
    asm volatile("s_waitcnt vmcnt(0)" ::: "memory");
    __builtin_amdgcn_s_barrier();
    __builtin_amdgcn_sched_barrier(0);

    // ---- S^T = K Q^T : 4 kv-subtiles x 8 k-chunks of 32x32x16
    f32x16 sacc[4] = {};
    __builtin_amdgcn_s_setprio(1);
#pragma unroll
    for (int ns = 0; ns < 4; ns++) {
      int row = ns * 32 + l31;
#pragma unroll
      for (int kc = 0; kc < 8; kc++) {
        int pc = (kc * 2 + hh) ^ (row & 15);
        bf16x8 ak = *(const bf16x8*)&Ks[row * 128 + pc * 8];
        sacc[ns] = __builtin_amdgcn_mfma_f32_32x32x16_bf16(ak, bq[kc], sacc[ns], 0, 0, 0);
      }
    }
    __builtin_amdgcn_s_setprio(0);

    // ---- mask (final tile only)
    if (kt + 128 > S_LEN) {
#pragma unroll
      for (int ns = 0; ns < 4; ns++)
#pragma unroll
        for (int r = 0; r < 16; r++) {
          int kvg = kt + ns * 32 + (r & 3) + 8 * (r >> 2) + 4 * hh;
          if (kvg >= S_LEN) sacc[ns][r] = -1e30f;
        }
    }

    // ---- online softmax (log2 domain), tree max over 64, permlane cross-half
    float mx;
    {
      float tm[8];
#pragma unroll
      for (int i = 0; i < 8; i++) {
        float a = fmaxf(fmaxf(sacc[0][i], sacc[0][i + 8]),
                        fmaxf(sacc[1][i], sacc[1][i + 8]));
        float b = fmaxf(fmaxf(sacc[2][i], sacc[2][i + 8]),
                        fmaxf(sacc[3][i], sacc[3][i + 8]));
        tm[i] = fmaxf(a, b);
      }
#pragma unroll
      for (int i = 0; i < 4; i++) tm[i] = fmaxf(tm[i], tm[i + 4]);
      mx = fmaxf(fmaxf(tm[0], tm[2]), fmaxf(tm[1], tm[3]));
    }
    mx = xhalf_max(mx);
    if (!__all(mx - m_i <= 11.5f)) {   // 11.5 ~= 8*log2(e)
      float mn = fmaxf(m_i, mx);
      float al = __builtin_amdgcn_exp2f(m_i - mn);
      l_i *= al;
#pragma unroll
      for (int dt = 0; dt < 4; dt++)
#pragma unroll
        for (int r = 0; r < 16; r++) oacc[dt][r] *= al;
      m_i = mn;
    }
#pragma unroll
    for (int ns = 0; ns < 4; ns++)
#pragma unroll
      for (int r = 0; r < 16; r++)
        sacc[ns][r] = __builtin_amdgcn_exp2f(sacc[ns][r] - m_i);
    float rs;
    {
      float ts[8];
#pragma unroll
      for (int i = 0; i < 8; i++)
        ts[i] = ((sacc[0][i] + sacc[0][i + 8]) + (sacc[1][i] + sacc[1][i + 8])) +
                ((sacc[2][i] + sacc[2][i + 8]) + (sacc[3][i] + sacc[3][i + 8]));
#pragma unroll
      for (int i = 0; i < 4; i++) ts[i] += ts[i + 4];
      rs = (ts[0] + ts[2]) + (ts[1] + ts[3]);
    }
    l_i += xhalf_sum(rs);

    // ---- O^T += V^T P^T : in-register P (T12), 8 kv-chunks of 32x32x16
    // chunk kvc (0..7): regs rb..rb+7 of sacc[kvc>>1], rb=(kvc&1)*8.
    // swap(w0,w2): r.x = low-kv word, r.y = high-kv word (m214-v22 recipe,
    // harness-verified in R3; mapping identical per-kvc).
    __builtin_amdgcn_s_setprio(1);
#pragma unroll
    for (int kvc = 0; kvc < 8; kvc++) {
      int ns = kvc >> 1, rb = (kvc & 1) * 8;
      int w0 = (int)pkbf(sacc[ns][rb + 0], sacc[ns][rb + 1]);
      int w1 = (int)pkbf(sacc[ns][rb + 2], sacc[ns][rb + 3]);
      int w2 = (int)pkbf(sacc[ns][rb + 4], sacc[ns][rb + 5]);
      int w3 = (int)pkbf(sacc[ns][rb + 6], sacc[ns][rb + 7]);
      i32x2 r02 = __builtin_amdgcn_permlane32_swap(w0, w2, false, false);
      i32x2 r13 = __builtin_amdgcn_permlane32_swap(w1, w3, false, false);
      union { unsigned int u[4]; bf16x8 v8; } bpu;
      bpu.u[0] = (unsigned int)r02.x; bpu.u[1] = (unsigned int)r13.x;
      bpu.u[2] = (unsigned int)r02.y; bpu.u[3] = (unsigned int)r13.y;
      bf16x8 bp = bpu.v8;
      int h2 = kvc >> 2, kvl = kvc & 3;
      const bf16_t* Vh = Vs + h2 * 8192;
#pragma unroll
      for (int dt = 0; dt < 4; dt++) {
        int d = dt * 32 + l31;
        int r = d >> 1;
        int cp = ((d & 1) << 3) | (kvl * 2 + hh);
        int pc = cp ^ (r & 15);
        bf16x8 av = *(const bf16x8*)&Vh[r * 128 + pc * 8];
        oacc[dt] = __builtin_amdgcn_mfma_f32_32x32x16_bf16(av, bp, oacc[dt], 0, 0, 0);
      }
    }
    __builtin_amdgcn_s_setprio(0);

    // ---- all waves done reading Ks/Vs before next stage overwrites
    asm volatile("s_waitcnt lgkmcnt(0)" ::: "memory");
    __builtin_amdgcn_s_barrier();
    __builtin_amdgcn_sched_barrier(0);
  }

  // ---- epilogue: O^T -> per-wave LDS transpose (scratch in dead Ks) -> global
  bf16_t* scr = Ks + w * (32 * 64);
  float inv = 1.f / l_i;
  int qr = lane >> 1, seg = lane & 1;
  int srow = s0 + w * 32 + qr;
#pragma unroll
  for (int half = 0; half < 2; half++) {
#pragma unroll
    for (int dl = 0; dl < 2; dl++) {
      int dt = half * 2 + dl;
#pragma unroll
      for (int tt = 0; tt < 4; tt++) {
        bf16x4 v;
#pragma unroll
        for (int r4 = 0; r4 < 4; r4++) v[r4] = (__bf16)(oacc[dt][tt * 4 + r4] * inv);
        int c8 = dl * 8 + 2 * tt + hh;          // d chunk (dl*32 + 8tt + 4hh)/4
        int pc8 = c8 ^ (l31 & 15);
        *(bf16x4*)&scr[l31 * 64 + pc8 * 4] = v;
      }
    }
    // same-wave DS ordering guarantees write->read visibility (per-wave region)
#pragma unroll
    for (int i = 0; i < 4; i++) {
      int c8 = seg * 8 + 2 * i;
      bf16x4 lo = *(const bf16x4*)&scr[qr * 64 + ((c8) ^ (qr & 15)) * 4];
      bf16x4 hi = *(const bf16x4*)&scr[qr * 64 + ((c8 + 1) ^ (qr & 15)) * 4];
      bf16x8 val;
#pragma unroll
      for (int j = 0; j < 4; j++) { val[j] = lo[j]; val[j + 4] = hi[j]; }
      if (srow < S_LEN)
        *(bf16x8*)&o[(size_t)srow * DIM + head * HD + half * 64 + seg * 32 + i * 8] = val;
    }
  }
}

// ---------------- launch ----------------

extern "C" void kernel_launch(void* const* d_in, const int* in_sizes, int n_in,
                              void* d_out, int out_size, void* d_ws, size_t ws_size,
                              hipStream_t stream) {
  const float* x    = (const float*)d_in[0];
  const float* q_w  = (const float*)d_in[1];
  const float* q_b  = (const float*)d_in[2];
  const float* k_w  = (const float*)d_in[3];
  const float* k_b  = (const float*)d_in[4];
  const float* v_w  = (const float*)d_in[5];
  const float* v_b  = (const float*)d_in[6];
  const float* o_w  = (const float*)d_in[7];
  const float* o_b  = (const float*)d_in[8];
  const float* nqw  = (const float*)d_in[9];
  const float* nkw  = (const float*)d_in[10];
  const float* fcos = (const float*)d_in[11];
  const float* fsin = (const float*)d_in[12];

  char* ws = (char*)d_ws;
  bf16_t* xb   = (bf16_t*)(ws + 0);          // 16,908,288 B
  bf16_t* wqkv = (bf16_t*)(ws + 16908288);   // 14,155,776 B
  bf16_t* wob  = (bf16_t*)(ws + 31064064);   //  4,718,592 B
  bf16_t* qkv  = (bf16_t*)(ws + 35782656);   // 50,724,864 B
  bf16_t* qb   = (bf16_t*)(ws + 86507520);   // 16,908,288 B
  bf16_t* kb   = (bf16_t*)(ws + 103415808);  // 16,908,288 B
  bf16_t* vtb  = (bf16_t*)(ws + 0);          // alias xb (dead after GEMM1); 12*128*5504*2 = 16,908,288 B exactly
  bf16_t* aob  = (bf16_t*)(ws + 35782656);   // alias qkv (dead after rope+transpose)

  cvt_x_kernel<<<(MPAD * DIM / 4 + 255) / 256, 256, 0, stream>>>(x, xb);
  cvt_wqkv_kernel<<<(NQKV * DIM / 4 + 255) / 256, 256, 0, stream>>>(q_w, k_w, v_w, wqkv);
  cvt_wo_kernel<<<(DIM * DIM / 4 + 255) / 256, 256, 0, stream>>>(o_w, wob);

  gemm_bt_kernel<true><<<dim3(NQKV / 128, MPAD / 128), 256, 0, stream>>>(
      xb, wqkv, qkv, q_b, k_b, v_b, MPAD, NQKV, DIM, MPAD);

  rope_qk_kernel<<<MPAD, 256, 0, stream>>>(qkv, nqw, nkw, fcos, fsin, qb, kb);
  v_transpose_kernel<<<dim3(SPAD / 64, NH), 256, 0, stream>>>(qkv, vtb);

  flash_attn_kernel<<<dim3((MPAD / 128) * NH), 256, 0, stream>>>(qb, kb, vtb, aob);

  gemm_bt_kernel<false><<<dim3(DIM / 128, MPAD / 128), 256, 0, stream>>>(
      aob, wob, d_out, o_b, o_b, o_b, MPAD, DIM, DIM, S_LEN);
}